// Round 3
// baseline (1793.543 us; speedup 1.0000x reference)
//
#include <hip/hip_runtime.h>

#define N_NODES 100000
#define N_EDGES 1600000
#define STRN 264        // node LDS row stride in ushorts (256 + 8 pad)
#define NBLK_SCAN 391   // ceil(100000/256)

typedef __attribute__((ext_vector_type(4))) float floatx4;
typedef __attribute__((ext_vector_type(8))) __bf16 bf16x8;
typedef __attribute__((ext_vector_type(8))) unsigned short ushort8;
typedef __attribute__((ext_vector_type(4))) unsigned short ushort4v;

// ---- ws layout (bytes) ----
#define WS_AGGR   0ull                        // 51,200,000  fp32 [N][128]
#define WS_COUNTS 51200000ull                 // 400,384     int[100096]
#define WS_OFFS   51600384ull
#define WS_PART   52000768ull                 // 2,048
#define WS_RANK   52002816ull                 // 6,400,000   int[E]
#define WS_PAIRS  58402816ull                 // 12,800,000  int2[E]
#define WS_WM1    71202816ull                 // 8,192   bf16 [128][32]
#define WS_W2     71211008ull                 // 32,768  bf16 [128][128]
#define WS_W3     71243776ull                 // 32,768
#define WS_WU1    71276544ull                 // 114,688 bf16 [224][256]
#define WS_WU2    71391232ull                 // 86,016  bf16 [192][224]
#define WS_WU3    71477248ull                 // 49,152  bf16 [128][192]
#define WS_BU1    71526400ull                 // 1,024   fp32 [224]
#define WS_BU2    71527424ull                 // 1,024   fp32 [192]

__device__ __forceinline__ unsigned short f2bf(float f) {
  return __builtin_bit_cast(unsigned short, (__bf16)f);  // RNE, v_cvt_pk_bf16_f32 on gfx950
}

__device__ __forceinline__ float leaky(float v) { return fmaxf(v, 0.01f * v); }

// ---------------- weight prep: fp32 -> bf16 (+ zero padding) ----------------
__global__ void prep_kernel(const float* __restrict__ Wm1, const float* __restrict__ Wm2,
                            const float* __restrict__ Wm3, const float* __restrict__ Wu1,
                            const float* __restrict__ Wu2, const float* __restrict__ Wu3,
                            const float* __restrict__ bu1, const float* __restrict__ bu2,
                            unsigned short* __restrict__ oWm1, unsigned short* __restrict__ o2,
                            unsigned short* __restrict__ o3, unsigned short* __restrict__ o1p,
                            unsigned short* __restrict__ o2p, unsigned short* __restrict__ o3p,
                            float* __restrict__ ob1, float* __restrict__ ob2) {
  int i = blockIdx.x * 256 + threadIdx.x;
  if (i < 4096) {                              // Wm1 pad [128][5] -> [128][32]
    int n = i >> 5, k = i & 31;
    oWm1[i] = (k < 5) ? f2bf(Wm1[n * 5 + k]) : (unsigned short)0;
  } else if (i < 20480) {
    int j = i - 4096; o2[j] = f2bf(Wm2[j]);
  } else if (i < 36864) {
    int j = i - 20480; o3[j] = f2bf(Wm3[j]);
  } else if (i < 94208) {                      // Wu1 pad [214][256] -> [224][256]
    int j = i - 36864; int n = j >> 8, k = j & 255;
    o1p[j] = (n < 214) ? f2bf(Wu1[n * 256 + k]) : (unsigned short)0;
  } else if (i < 137216) {                     // Wu2 pad [172][214] -> [192][224]
    int j = i - 94208; int n = j / 224, k = j - n * 224;
    o2p[j] = (n < 172 && k < 214) ? f2bf(Wu2[n * 214 + k]) : (unsigned short)0;
  } else if (i < 161792) {                     // Wu3 pad [128][172] -> [128][192]
    int j = i - 137216; int n = j / 192, k = j - n * 192;
    o3p[j] = (k < 172) ? f2bf(Wu3[n * 172 + k]) : (unsigned short)0;
  } else if (i < 162016) {                     // bu1 pad [214] -> [224]
    int j = i - 161792; ob1[j] = (j < 214) ? bu1[j] : 0.f;
  } else if (i < 162208) {                     // bu2 pad [172] -> [192]
    int j = i - 162016; ob2[j] = (j < 172) ? bu2[j] : 0.f;
  }
}

// ---------------- counting sort of edges by dst (rank-in-hist, atomic-free scatter) ----
__global__ void hist_kernel(const int* __restrict__ dst, int* __restrict__ counts,
                            int* __restrict__ rank) {
  int e = blockIdx.x * 256 + threadIdx.x;
  if (e < N_EDGES) rank[e] = atomicAdd(&counts[dst[e]], 1);
}

__global__ void scanA_kernel(const int* __restrict__ counts, int* __restrict__ offs,
                             int* __restrict__ partials) {
  __shared__ int tmp[256];
  const int t = threadIdx.x;
  const int i = blockIdx.x * 256 + t;
  int v = (i < N_NODES) ? counts[i] : 0;
  tmp[t] = v;
  __syncthreads();
  for (int off = 1; off < 256; off <<= 1) {
    int a = (t >= off) ? tmp[t - off] : 0;
    __syncthreads();
    tmp[t] += a;
    __syncthreads();
  }
  if (i < N_NODES) offs[i] = tmp[t] - v;  // exclusive
  if (t == 255) partials[blockIdx.x] = tmp[255];
}

__global__ void scanB_kernel(int* __restrict__ partials) {
  __shared__ int tmp[512];
  const int t = threadIdx.x;
  int v = (t < NBLK_SCAN) ? partials[t] : 0;
  tmp[t] = v;
  __syncthreads();
  for (int off = 1; off < 512; off <<= 1) {
    int a = (t >= off) ? tmp[t - off] : 0;
    __syncthreads();
    tmp[t] += a;
    __syncthreads();
  }
  if (t < NBLK_SCAN) partials[t] = tmp[t] - v;  // exclusive
}

__global__ void scanC_kernel(int* __restrict__ offs, const int* __restrict__ partials) {
  int i = blockIdx.x * 256 + threadIdx.x;
  if (i < N_NODES) offs[i] += partials[blockIdx.x];
}

__global__ void scatter_kernel(const int* __restrict__ dst, const int* __restrict__ rank,
                               const int* __restrict__ offs, int2* __restrict__ pairs) {
  int e = blockIdx.x * 256 + threadIdx.x;
  if (e < N_EDGES) {
    int d = dst[e];
    pairs[offs[d] + rank[e]] = make_int2(e, d);
  }
}

// ---------------- edge kernel ----------------
// Swapped-operand MFMA: D = W-frags(A, global) x h-frags(B, LDS) -> D[m=ch][n=edge].
// C-layout gives 4 consecutive CHANNELS per lane -> b64 epilogue writes.
// All sH rows are wave-private (wave owns edges [wave*32, wave*32+32)) -> no barriers.
// sH swizzle: chunk(8ch) ^ (edge&15) keeps all b64/b128 accesses <=2-way.
template <bool LEAKY>
__device__ __forceinline__ void edge_layer128(unsigned short* __restrict__ sH,
                                              const unsigned short* __restrict__ Wg,
                                              const float* __restrict__ bias,
                                              int eb, int col, int q) {
  floatx4 acc[2][8];
#pragma unroll
  for (int i = 0; i < 2; i++)
#pragma unroll
    for (int j = 0; j < 8; j++) acc[i][j] = (floatx4){0.f, 0.f, 0.f, 0.f};
#pragma unroll
  for (int ks = 0; ks < 4; ks++) {
    const int kk = ks * 32 + q * 8;
    const int kswz = kk ^ (col << 3);
    bf16x8 b0 = *(const bf16x8*)(const void*)&sH[(eb + col) * 128 + kswz];
    bf16x8 b1 = *(const bf16x8*)(const void*)&sH[(eb + 16 + col) * 128 + kswz];
#pragma unroll
    for (int nt = 0; nt < 8; nt++) {
      bf16x8 aw = *(const bf16x8*)(const void*)&Wg[(nt * 16 + col) * 128 + kk];
      acc[0][nt] = __builtin_amdgcn_mfma_f32_16x16x32_bf16(aw, b0, acc[0][nt], 0, 0, 0);
      acc[1][nt] = __builtin_amdgcn_mfma_f32_16x16x32_bf16(aw, b1, acc[1][nt], 0, 0, 0);
    }
  }
#pragma unroll
  for (int nt = 0; nt < 8; nt++) {
    const int ch = nt * 16 + q * 4;
    float4 bv = *(const float4*)(const void*)&bias[ch];
    float bvv[4] = {bv.x, bv.y, bv.z, bv.w};
#pragma unroll
    for (int i = 0; i < 2; i++) {
      const int e = eb + i * 16 + col;
      ushort4v pk;
#pragma unroll
      for (int r = 0; r < 4; r++) {
        float v = acc[i][nt][r] + bvv[r];
        if (LEAKY) v = leaky(v);
        pk[r] = f2bf(v);
      }
      *(ushort4v*)(void*)&sH[e * 128 + (ch ^ (col << 3))] = pk;
    }
  }
}

__global__ __launch_bounds__(256, 3) void edge_kernel(
    const float* __restrict__ attr, const int2* __restrict__ pairs,
    const unsigned short* __restrict__ Wm1p, const float* __restrict__ bm1,
    const unsigned short* __restrict__ W2bf, const float* __restrict__ bm2,
    const unsigned short* __restrict__ W3bf, const float* __restrict__ bm3,
    float* __restrict__ aggr) {
  __shared__ unsigned short sH[128 * 128];    // 32 KB [edge][ch] bf16, swizzled
  __shared__ unsigned short sAttr[128 * 40];  // 10 KB [edge][32k] bf16, stride-40 pad
  __shared__ int sPerm[128];
  __shared__ int sDst[128];

  const int t = threadIdx.x;
  const int wave = t >> 6, lane = t & 63;
  const int col = lane & 15, q = lane >> 4;
  const int eb = wave * 32;
  const long blockEdge = (long)blockIdx.x * 128;

  // ---- stage pairs (wave-private rows) ----
  if (lane < 32) {
    int2 p = pairs[blockEdge + eb + lane];
    sPerm[eb + lane] = p.x;
    sDst[eb + lane] = p.y;
  }
  // ---- zero + gather attr (bf16) into wave's sAttr rows ----
  {
    ushort8 z = {0, 0, 0, 0, 0, 0, 0, 0};
    const int base = eb * 40;
    *(ushort8*)(void*)&sAttr[base + lane * 8] = z;
    *(ushort8*)(void*)&sAttr[base + (lane + 64) * 8] = z;
    if (lane < 32) *(ushort8*)(void*)&sAttr[base + (lane + 128) * 8] = z;
  }
  {
    const int e = eb + (lane >> 1);
    const float* ap = attr + (size_t)sPerm[e] * 5;
    if ((lane & 1) == 0) {
      sAttr[e * 40 + 0] = f2bf(ap[0]);
      sAttr[e * 40 + 1] = f2bf(ap[1]);
      sAttr[e * 40 + 2] = f2bf(ap[2]);
    } else {
      sAttr[e * 40 + 3] = f2bf(ap[3]);
      sAttr[e * 40 + 4] = f2bf(ap[4]);
    }
  }

  // ---- layer 1 (K=32, MFMA) ----
  {
    floatx4 acc[2][8];
#pragma unroll
    for (int i = 0; i < 2; i++)
#pragma unroll
      for (int j = 0; j < 8; j++) acc[i][j] = (floatx4){0.f, 0.f, 0.f, 0.f};
    const int kk = q * 8;
    bf16x8 b0 = *(const bf16x8*)(const void*)&sAttr[(eb + col) * 40 + kk];
    bf16x8 b1 = *(const bf16x8*)(const void*)&sAttr[(eb + 16 + col) * 40 + kk];
#pragma unroll
    for (int nt = 0; nt < 8; nt++) {
      bf16x8 aw = *(const bf16x8*)(const void*)&Wm1p[(nt * 16 + col) * 32 + kk];
      acc[0][nt] = __builtin_amdgcn_mfma_f32_16x16x32_bf16(aw, b0, acc[0][nt], 0, 0, 0);
      acc[1][nt] = __builtin_amdgcn_mfma_f32_16x16x32_bf16(aw, b1, acc[1][nt], 0, 0, 0);
    }
#pragma unroll
    for (int nt = 0; nt < 8; nt++) {
      const int ch = nt * 16 + q * 4;
      float4 bv = *(const float4*)(const void*)&bm1[ch];
      float bvv[4] = {bv.x, bv.y, bv.z, bv.w};
#pragma unroll
      for (int i = 0; i < 2; i++) {
        const int e = eb + i * 16 + col;
        ushort4v pk;
#pragma unroll
        for (int r = 0; r < 4; r++) pk[r] = f2bf(leaky(acc[i][nt][r] + bvv[r]));
        *(ushort4v*)(void*)&sH[e * 128 + (ch ^ (col << 3))] = pk;
      }
    }
  }

  // ---- layers 2 & 3 ----
  edge_layer128<true>(sH, W2bf, bm2, eb, col, q);
  edge_layer128<false>(sH, W3bf, bm3, eb, col, q);  // msg (bf16) now in sH

  // ---- segmented walk: lane = (8-ch chunk) x (8-edge group), wave-private ----
  {
    const int cg = lane & 15;
    const int eg = lane >> 4;
    float a8[8];
#pragma unroll
    for (int j = 0; j < 8; j++) a8[j] = 0.f;
    int dprev = sDst[eb + eg * 8];
#pragma unroll
    for (int e8 = 0; e8 < 8; e8++) {
      const int el = eg * 8 + e8;
      int d = sDst[eb + el];
      if (d != dprev) {
#pragma unroll
        for (int j = 0; j < 8; j++) atomicAdd(&aggr[(size_t)dprev * 128 + cg * 8 + j], a8[j]);
#pragma unroll
        for (int j = 0; j < 8; j++) a8[j] = 0.f;
        dprev = d;
      }
      ushort8 m = *(const ushort8*)(const void*)&sH[(eb + el) * 128 + ((cg * 8) ^ ((el & 15) << 3))];
#pragma unroll
      for (int j = 0; j < 8; j++) {
        unsigned u = ((unsigned)m[j]) << 16;
        a8[j] += __builtin_bit_cast(float, u);
      }
    }
#pragma unroll
    for (int j = 0; j < 8; j++) atomicAdd(&aggr[(size_t)dprev * 128 + cg * 8 + j], a8[j]);
  }
}

// ---------------- node layer (swapped-operand MFMA, wave-private rows) ----------------
template <int NT, int KST, bool FINAL>
__device__ __forceinline__ void layer_node(unsigned short* __restrict__ sX,
                                           const unsigned short* __restrict__ W,
                                           const float* __restrict__ biasP,
                                           int wave, int lane, int nodeGBase,
                                           float* __restrict__ out) {
  const int col = lane & 15, q = lane >> 4;
  const int row = wave * 16 + col;
  floatx4 acc[NT];
#pragma unroll
  for (int i = 0; i < NT; i++) acc[i] = (floatx4){0.f, 0.f, 0.f, 0.f};
#pragma unroll
  for (int ks = 0; ks < KST; ks++) {
    const int kk = ks * 32 + q * 8;
    bf16x8 b = *(const bf16x8*)(const void*)&sX[row * STRN + kk];
#pragma unroll
    for (int nt = 0; nt < NT; nt++) {
      bf16x8 aw = *(const bf16x8*)(const void*)&W[(nt * 16 + col) * (KST * 32) + kk];
      acc[nt] = __builtin_amdgcn_mfma_f32_16x16x32_bf16(aw, b, acc[nt], 0, 0, 0);
    }
  }
#pragma unroll
  for (int nt = 0; nt < NT; nt++) {
    const int ch = nt * 16 + q * 4;
    float4 bv = *(const float4*)(const void*)&biasP[ch];
    float bvv[4] = {bv.x, bv.y, bv.z, bv.w};
    if (!FINAL) {
      ushort4v pk;
#pragma unroll
      for (int r = 0; r < 4; r++) pk[r] = f2bf(leaky(acc[nt][r] + bvv[r]));
      *(ushort4v*)(void*)&sX[row * STRN + ch] = pk;
    } else {
      const long ng = (long)nodeGBase + row;
      if (ng < N_NODES) {
        float4 o;
        o.x = acc[nt][0] + bvv[0];
        o.y = acc[nt][1] + bvv[1];
        o.z = acc[nt][2] + bvv[2];
        o.w = acc[nt][3] + bvv[3];
        *(float4*)(void*)&out[ng * 128 + ch] = o;
      }
    }
  }
}

// ---------------- node kernel: LN(concat) + MLP, barrier-free ----------------
__global__ __launch_bounds__(256, 3) void node_kernel(
    const float* __restrict__ x, const float* __restrict__ aggr,
    const float* __restrict__ lng, const float* __restrict__ lnb,
    const unsigned short* __restrict__ Wu1p, const float* __restrict__ bu1p,
    const unsigned short* __restrict__ Wu2p, const float* __restrict__ bu2p,
    const unsigned short* __restrict__ Wu3p, const float* __restrict__ bu3,
    float* __restrict__ out) {
  __shared__ unsigned short sX[64 * STRN];  // [node][c] bf16, padded stride
  const int t = threadIdx.x;
  const int wave = t >> 6, lane = t & 63;

  // LayerNorm over cat=[x,aggr] (fp32). 4 threads per node (same wave).
  const int nl = t >> 2;
  const int part = t & 3;
  const long nodeG = (long)blockIdx.x * 64 + nl;
  const bool valid = nodeG < N_NODES;
  const float* src = (part < 2) ? (x + nodeG * 128 + part * 64)
                                : (aggr + nodeG * 128 + (part - 2) * 64);
  float s = 0.f, ss = 0.f;
  if (valid) {
#pragma unroll
    for (int i = 0; i < 16; i++) {
      float4 a = *(const float4*)(src + i * 4);
      s += a.x + a.y + a.z + a.w;
      ss += a.x * a.x + a.y * a.y + a.z * a.z + a.w * a.w;
    }
  }
  s += __shfl_xor(s, 1); s += __shfl_xor(s, 2);
  ss += __shfl_xor(ss, 1); ss += __shfl_xor(ss, 2);
  const float mean = s * (1.f / 256.f);
  const float var = ss * (1.f / 256.f) - mean * mean;
  const float rstd = rsqrtf(var + 1e-5f);
  const int cb = part * 64;
#pragma unroll
  for (int i = 0; i < 16; i++) {
    float4 a = valid ? *(const float4*)(src + i * 4) : make_float4(0.f, 0.f, 0.f, 0.f);
    int c = cb + i * 4;
    float4 g = *(const float4*)(const void*)&lng[c];
    float4 bb = *(const float4*)(const void*)&lnb[c];
    ushort4v p;
    p[0] = f2bf((a.x - mean) * rstd * g.x + bb.x);
    p[1] = f2bf((a.y - mean) * rstd * g.y + bb.y);
    p[2] = f2bf((a.z - mean) * rstd * g.z + bb.z);
    p[3] = f2bf((a.w - mean) * rstd * g.w + bb.w);
    *(ushort4v*)(void*)&sX[nl * STRN + c] = p;
  }

  const int nodeGBase = blockIdx.x * 64;
  layer_node<14, 8, false>(sX, Wu1p, bu1p, wave, lane, nodeGBase, nullptr);
  layer_node<12, 7, false>(sX, Wu2p, bu2p, wave, lane, nodeGBase, nullptr);
  layer_node<8, 6, true>(sX, Wu3p, bu3, wave, lane, nodeGBase, out);
}

// ---------------- launch ----------------
extern "C" void kernel_launch(void* const* d_in, const int* in_sizes, int n_in,
                              void* d_out, int out_size, void* d_ws, size_t ws_size,
                              hipStream_t stream) {
  const float* x    = (const float*)d_in[0];
  const int*   eidx = (const int*)d_in[1];
  const float* attr = (const float*)d_in[2];
  const float* Wm1  = (const float*)d_in[3];
  const float* bm1  = (const float*)d_in[4];
  const float* Wm2  = (const float*)d_in[5];
  const float* bm2  = (const float*)d_in[6];
  const float* Wm3  = (const float*)d_in[7];
  const float* bm3  = (const float*)d_in[8];
  const float* lng  = (const float*)d_in[9];
  const float* lnb  = (const float*)d_in[10];
  const float* Wu1  = (const float*)d_in[11];
  const float* bu1  = (const float*)d_in[12];
  const float* Wu2  = (const float*)d_in[13];
  const float* bu2  = (const float*)d_in[14];
  const float* Wu3  = (const float*)d_in[15];
  const float* bu3  = (const float*)d_in[16];
  float* out = (float*)d_out;

  char* ws = (char*)d_ws;
  float* aggr = (float*)(ws + WS_AGGR);
  int* counts = (int*)(ws + WS_COUNTS);
  int* offs   = (int*)(ws + WS_OFFS);
  int* parts  = (int*)(ws + WS_PART);
  int* rank   = (int*)(ws + WS_RANK);
  int2* pairs = (int2*)(ws + WS_PAIRS);
  unsigned short* Wm1p = (unsigned short*)(ws + WS_WM1);
  unsigned short* W2bf = (unsigned short*)(ws + WS_W2);
  unsigned short* W3bf = (unsigned short*)(ws + WS_W3);
  unsigned short* Wu1p = (unsigned short*)(ws + WS_WU1);
  unsigned short* Wu2p = (unsigned short*)(ws + WS_WU2);
  unsigned short* Wu3p = (unsigned short*)(ws + WS_WU3);
  float* bu1p = (float*)(ws + WS_BU1);
  float* bu2p = (float*)(ws + WS_BU2);

  const int* dst = eidx + N_EDGES;  // edge_index[1]

  hipMemsetAsync(counts, 0, 400384, stream);
  hipMemsetAsync(aggr, 0, (size_t)N_NODES * 128 * sizeof(float), stream);
  prep_kernel<<<634, 256, 0, stream>>>(Wm1, Wm2, Wm3, Wu1, Wu2, Wu3, bu1, bu2,
                                       Wm1p, W2bf, W3bf, Wu1p, Wu2p, Wu3p, bu1p, bu2p);

  hist_kernel<<<6250, 256, 0, stream>>>(dst, counts, rank);
  scanA_kernel<<<NBLK_SCAN, 256, 0, stream>>>(counts, offs, parts);
  scanB_kernel<<<1, 512, 0, stream>>>(parts);
  scanC_kernel<<<NBLK_SCAN, 256, 0, stream>>>(offs, parts);
  scatter_kernel<<<6250, 256, 0, stream>>>(dst, rank, offs, pairs);

  edge_kernel<<<N_EDGES / 128, 256, 0, stream>>>(attr, pairs, Wm1p, bm1, W2bf, bm2, W3bf,
                                                 bm3, aggr);
  node_kernel<<<(N_NODES + 63) / 64, 256, 0, stream>>>(x, aggr, lng, lnb, Wu1p, bu1p, Wu2p,
                                                       bu2p, Wu3p, bu3, out);
}

// Round 4
// 952.305 us; speedup vs baseline: 1.8834x; 1.8834x over previous
//
#include <hip/hip_runtime.h>

#define N_NODES 100000
#define N_EDGES 1600000
#define STRN 264        // node LDS row stride in ushorts (256 + 8 pad)
#define NBLK_SCAN 391   // ceil(100000/256)

typedef __attribute__((ext_vector_type(4))) float floatx4;
typedef __attribute__((ext_vector_type(8))) __bf16 bf16x8;
typedef __attribute__((ext_vector_type(8))) unsigned short ushort8;
typedef __attribute__((ext_vector_type(4))) unsigned short ushort4v;

// ---- ws layout (bytes) ----
#define WS_AGGR   0ull                        // 51,200,000  fp32 [N][128]
#define WS_COUNTS 51200000ull                 // 400,384     int[100096]
#define WS_OFFS   51600384ull
#define WS_PART   52000768ull                 // 2,048
#define WS_RANK   52002816ull                 // 6,400,000   int[E]
#define WS_PAIRS  58402816ull                 // 12,800,000  int2[E]
#define WS_WM1    71202816ull                 // 8,192   bf16 [128][32]
#define WS_W2     71211008ull                 // 32,768  bf16 [128][128]
#define WS_W3     71243776ull                 // 32,768
#define WS_WU1    71276544ull                 // 114,688 bf16 [224][256]
#define WS_WU2    71391232ull                 // 86,016  bf16 [192][224]
#define WS_WU3    71477248ull                 // 49,152  bf16 [128][192]
#define WS_BU1    71526400ull                 // 1,024   fp32 [224]
#define WS_BU2    71527424ull                 // 1,024   fp32 [192]

__device__ __forceinline__ unsigned short f2bf(float f) {
  return __builtin_bit_cast(unsigned short, (__bf16)f);  // RNE, v_cvt_pk_bf16_f32 on gfx950
}

__device__ __forceinline__ float leaky(float v) { return fmaxf(v, 0.01f * v); }

// ---------------- weight prep: fp32 -> bf16 (+ zero padding) ----------------
__global__ void prep_kernel(const float* __restrict__ Wm1, const float* __restrict__ Wm2,
                            const float* __restrict__ Wm3, const float* __restrict__ Wu1,
                            const float* __restrict__ Wu2, const float* __restrict__ Wu3,
                            const float* __restrict__ bu1, const float* __restrict__ bu2,
                            unsigned short* __restrict__ oWm1, unsigned short* __restrict__ o2,
                            unsigned short* __restrict__ o3, unsigned short* __restrict__ o1p,
                            unsigned short* __restrict__ o2p, unsigned short* __restrict__ o3p,
                            float* __restrict__ ob1, float* __restrict__ ob2) {
  int i = blockIdx.x * 256 + threadIdx.x;
  if (i < 4096) {                              // Wm1 pad [128][5] -> [128][32]
    int n = i >> 5, k = i & 31;
    oWm1[i] = (k < 5) ? f2bf(Wm1[n * 5 + k]) : (unsigned short)0;
  } else if (i < 20480) {
    int j = i - 4096; o2[j] = f2bf(Wm2[j]);
  } else if (i < 36864) {
    int j = i - 20480; o3[j] = f2bf(Wm3[j]);
  } else if (i < 94208) {                      // Wu1 pad [214][256] -> [224][256]
    int j = i - 36864; int n = j >> 8, k = j & 255;
    o1p[j] = (n < 214) ? f2bf(Wu1[n * 256 + k]) : (unsigned short)0;
  } else if (i < 137216) {                     // Wu2 pad [172][214] -> [192][224]
    int j = i - 94208; int n = j / 224, k = j - n * 224;
    o2p[j] = (n < 172 && k < 214) ? f2bf(Wu2[n * 214 + k]) : (unsigned short)0;
  } else if (i < 161792) {                     // Wu3 pad [128][172] -> [128][192]
    int j = i - 137216; int n = j / 192, k = j - n * 192;
    o3p[j] = (k < 172) ? f2bf(Wu3[n * 172 + k]) : (unsigned short)0;
  } else if (i < 162016) {                     // bu1 pad [214] -> [224]
    int j = i - 161792; ob1[j] = (j < 214) ? bu1[j] : 0.f;
  } else if (i < 162208) {                     // bu2 pad [172] -> [192]
    int j = i - 162016; ob2[j] = (j < 172) ? bu2[j] : 0.f;
  }
}

// ---------------- counting sort of edges by dst (rank-in-hist, atomic-free scatter) ----
__global__ void hist_kernel(const int* __restrict__ dst, int* __restrict__ counts,
                            int* __restrict__ rank) {
  int e = blockIdx.x * 256 + threadIdx.x;
  if (e < N_EDGES) rank[e] = atomicAdd(&counts[dst[e]], 1);
}

__global__ void scanA_kernel(const int* __restrict__ counts, int* __restrict__ offs,
                             int* __restrict__ partials) {
  __shared__ int tmp[256];
  const int t = threadIdx.x;
  const int i = blockIdx.x * 256 + t;
  int v = (i < N_NODES) ? counts[i] : 0;
  tmp[t] = v;
  __syncthreads();
  for (int off = 1; off < 256; off <<= 1) {
    int a = (t >= off) ? tmp[t - off] : 0;
    __syncthreads();
    tmp[t] += a;
    __syncthreads();
  }
  if (i < N_NODES) offs[i] = tmp[t] - v;  // exclusive
  if (t == 255) partials[blockIdx.x] = tmp[255];
}

__global__ void scanB_kernel(int* __restrict__ partials) {
  __shared__ int tmp[512];
  const int t = threadIdx.x;
  int v = (t < NBLK_SCAN) ? partials[t] : 0;
  tmp[t] = v;
  __syncthreads();
  for (int off = 1; off < 512; off <<= 1) {
    int a = (t >= off) ? tmp[t - off] : 0;
    __syncthreads();
    tmp[t] += a;
    __syncthreads();
  }
  if (t < NBLK_SCAN) partials[t] = tmp[t] - v;  // exclusive
}

__global__ void scanC_kernel(int* __restrict__ offs, const int* __restrict__ partials) {
  int i = blockIdx.x * 256 + threadIdx.x;
  if (i < N_NODES) offs[i] += partials[blockIdx.x];
}

__global__ void scatter_kernel(const int* __restrict__ dst, const int* __restrict__ rank,
                               const int* __restrict__ offs, int2* __restrict__ pairs) {
  int e = blockIdx.x * 256 + threadIdx.x;
  if (e < N_EDGES) {
    int d = dst[e];
    pairs[offs[d] + rank[e]] = make_int2(e, d);
  }
}

// ---------------- edge kernel ----------------
// Swapped-operand MFMA: D = W-frags(A, global) x h-frags(B, LDS) -> D[m=ch][n=edge].
// C-layout gives 4 consecutive CHANNELS per lane -> b64 epilogue writes.
// All sH rows are wave-private (wave owns edges [wave*32, wave*32+32)) -> no barriers.
// sH swizzle: chunk(8ch) ^ (edge&15) keeps all b64/b128 accesses <=2-way.
template <bool LEAKY>
__device__ __forceinline__ void edge_layer128(unsigned short* __restrict__ sH,
                                              const unsigned short* __restrict__ Wg,
                                              const float* __restrict__ bias,
                                              int eb, int col, int q) {
  floatx4 acc[2][8];
#pragma unroll
  for (int i = 0; i < 2; i++)
#pragma unroll
    for (int j = 0; j < 8; j++) acc[i][j] = (floatx4){0.f, 0.f, 0.f, 0.f};
#pragma unroll
  for (int ks = 0; ks < 4; ks++) {
    const int kk = ks * 32 + q * 8;
    const int kswz = kk ^ (col << 3);
    bf16x8 b0 = *(const bf16x8*)(const void*)&sH[(eb + col) * 128 + kswz];
    bf16x8 b1 = *(const bf16x8*)(const void*)&sH[(eb + 16 + col) * 128 + kswz];
#pragma unroll
    for (int nt = 0; nt < 8; nt++) {
      bf16x8 aw = *(const bf16x8*)(const void*)&Wg[(nt * 16 + col) * 128 + kk];
      acc[0][nt] = __builtin_amdgcn_mfma_f32_16x16x32_bf16(aw, b0, acc[0][nt], 0, 0, 0);
      acc[1][nt] = __builtin_amdgcn_mfma_f32_16x16x32_bf16(aw, b1, acc[1][nt], 0, 0, 0);
    }
  }
#pragma unroll
  for (int nt = 0; nt < 8; nt++) {
    const int ch = nt * 16 + q * 4;
    float4 bv = *(const float4*)(const void*)&bias[ch];
    float bvv[4] = {bv.x, bv.y, bv.z, bv.w};
#pragma unroll
    for (int i = 0; i < 2; i++) {
      const int e = eb + i * 16 + col;
      ushort4v pk;
#pragma unroll
      for (int r = 0; r < 4; r++) {
        float v = acc[i][nt][r] + bvv[r];
        if (LEAKY) v = leaky(v);
        pk[r] = f2bf(v);
      }
      *(ushort4v*)(void*)&sH[e * 128 + (ch ^ (col << 3))] = pk;
    }
  }
}

__global__ __launch_bounds__(256, 3) void edge_kernel(
    const float* __restrict__ attr, const int2* __restrict__ pairs,
    const unsigned short* __restrict__ Wm1p, const float* __restrict__ bm1,
    const unsigned short* __restrict__ W2bf, const float* __restrict__ bm2,
    const unsigned short* __restrict__ W3bf, const float* __restrict__ bm3,
    float* __restrict__ aggr) {
  __shared__ unsigned short sH[128 * 128];    // 32 KB [edge][ch] bf16, swizzled
  __shared__ unsigned short sAttr[128 * 40];  // 10 KB [edge][32k] bf16, stride-40 pad
  __shared__ int sPerm[128];
  __shared__ int sDst[128];

  const int t = threadIdx.x;
  const int wave = t >> 6, lane = t & 63;
  const int col = lane & 15, q = lane >> 4;
  const int eb = wave * 32;
  const long blockEdge = (long)blockIdx.x * 128;

  // ---- stage pairs (wave-private rows) ----
  if (lane < 32) {
    int2 p = pairs[blockEdge + eb + lane];
    sPerm[eb + lane] = p.x;
    sDst[eb + lane] = p.y;
  }
  // ---- zero + gather attr (bf16) into wave's sAttr rows ----
  {
    ushort8 z = {0, 0, 0, 0, 0, 0, 0, 0};
    const int base = eb * 40;
    *(ushort8*)(void*)&sAttr[base + lane * 8] = z;
    *(ushort8*)(void*)&sAttr[base + (lane + 64) * 8] = z;
    if (lane < 32) *(ushort8*)(void*)&sAttr[base + (lane + 128) * 8] = z;
  }
  {
    const int e = eb + (lane >> 1);
    const float* ap = attr + (size_t)sPerm[e] * 5;
    if ((lane & 1) == 0) {
      sAttr[e * 40 + 0] = f2bf(ap[0]);
      sAttr[e * 40 + 1] = f2bf(ap[1]);
      sAttr[e * 40 + 2] = f2bf(ap[2]);
    } else {
      sAttr[e * 40 + 3] = f2bf(ap[3]);
      sAttr[e * 40 + 4] = f2bf(ap[4]);
    }
  }

  // ---- layer 1 (K=32, MFMA) ----
  {
    floatx4 acc[2][8];
#pragma unroll
    for (int i = 0; i < 2; i++)
#pragma unroll
      for (int j = 0; j < 8; j++) acc[i][j] = (floatx4){0.f, 0.f, 0.f, 0.f};
    const int kk = q * 8;
    bf16x8 b0 = *(const bf16x8*)(const void*)&sAttr[(eb + col) * 40 + kk];
    bf16x8 b1 = *(const bf16x8*)(const void*)&sAttr[(eb + 16 + col) * 40 + kk];
#pragma unroll
    for (int nt = 0; nt < 8; nt++) {
      bf16x8 aw = *(const bf16x8*)(const void*)&Wm1p[(nt * 16 + col) * 32 + kk];
      acc[0][nt] = __builtin_amdgcn_mfma_f32_16x16x32_bf16(aw, b0, acc[0][nt], 0, 0, 0);
      acc[1][nt] = __builtin_amdgcn_mfma_f32_16x16x32_bf16(aw, b1, acc[1][nt], 0, 0, 0);
    }
#pragma unroll
    for (int nt = 0; nt < 8; nt++) {
      const int ch = nt * 16 + q * 4;
      float4 bv = *(const float4*)(const void*)&bm1[ch];
      float bvv[4] = {bv.x, bv.y, bv.z, bv.w};
#pragma unroll
      for (int i = 0; i < 2; i++) {
        const int e = eb + i * 16 + col;
        ushort4v pk;
#pragma unroll
        for (int r = 0; r < 4; r++) pk[r] = f2bf(leaky(acc[i][nt][r] + bvv[r]));
        *(ushort4v*)(void*)&sH[e * 128 + (ch ^ (col << 3))] = pk;
      }
    }
  }

  // ---- layers 2 & 3 ----
  edge_layer128<true>(sH, W2bf, bm2, eb, col, q);
  edge_layer128<false>(sH, W3bf, bm3, eb, col, q);  // msg (bf16) now in sH

  // ---- segmented walk: lane = channel (c and c+64); wave walks its 32 sorted edges.
  // Atomic instruction = 64 lanes x consecutive channels = 256 B contiguous -> full-line
  // writebacks in TCC (this is what keeps WRITE_SIZE ~= 4B x atomic count).
  {
    const int c = lane;
    float a0 = 0.f, a1 = 0.f;
    int dprev = sDst[eb];
#pragma unroll 4
    for (int e = 0; e < 32; e++) {
      const int d = sDst[eb + e];  // wave-uniform broadcast
      if (d != dprev) {
        atomicAdd(&aggr[(size_t)dprev * 128 + c], a0);
        atomicAdd(&aggr[(size_t)dprev * 128 + c + 64], a1);
        a0 = 0.f; a1 = 0.f;
        dprev = d;
      }
      const int r = eb + e;
      const int s = (r & 15) << 3;
      unsigned m0 = sH[r * 128 + (c ^ s)];
      unsigned m1 = sH[r * 128 + ((c + 64) ^ s)];
      a0 += __builtin_bit_cast(float, m0 << 16);
      a1 += __builtin_bit_cast(float, m1 << 16);
    }
    atomicAdd(&aggr[(size_t)dprev * 128 + c], a0);
    atomicAdd(&aggr[(size_t)dprev * 128 + c + 64], a1);
  }
}

// ---------------- node layer (swapped-operand MFMA, wave-private rows) ----------------
template <int NT, int KST, bool FINAL>
__device__ __forceinline__ void layer_node(unsigned short* __restrict__ sX,
                                           const unsigned short* __restrict__ W,
                                           const float* __restrict__ biasP,
                                           int wave, int lane, int nodeGBase,
                                           float* __restrict__ out) {
  const int col = lane & 15, q = lane >> 4;
  const int row = wave * 16 + col;
  floatx4 acc[NT];
#pragma unroll
  for (int i = 0; i < NT; i++) acc[i] = (floatx4){0.f, 0.f, 0.f, 0.f};
#pragma unroll
  for (int ks = 0; ks < KST; ks++) {
    const int kk = ks * 32 + q * 8;
    bf16x8 b = *(const bf16x8*)(const void*)&sX[row * STRN + kk];
#pragma unroll
    for (int nt = 0; nt < NT; nt++) {
      bf16x8 aw = *(const bf16x8*)(const void*)&W[(nt * 16 + col) * (KST * 32) + kk];
      acc[nt] = __builtin_amdgcn_mfma_f32_16x16x32_bf16(aw, b, acc[nt], 0, 0, 0);
    }
  }
#pragma unroll
  for (int nt = 0; nt < NT; nt++) {
    const int ch = nt * 16 + q * 4;
    float4 bv = *(const float4*)(const void*)&biasP[ch];
    float bvv[4] = {bv.x, bv.y, bv.z, bv.w};
    if (!FINAL) {
      ushort4v pk;
#pragma unroll
      for (int r = 0; r < 4; r++) pk[r] = f2bf(leaky(acc[nt][r] + bvv[r]));
      *(ushort4v*)(void*)&sX[row * STRN + ch] = pk;
    } else {
      const long ng = (long)nodeGBase + row;
      if (ng < N_NODES) {
        float4 o;
        o.x = acc[nt][0] + bvv[0];
        o.y = acc[nt][1] + bvv[1];
        o.z = acc[nt][2] + bvv[2];
        o.w = acc[nt][3] + bvv[3];
        *(float4*)(void*)&out[ng * 128 + ch] = o;
      }
    }
  }
}

// ---------------- node kernel: LN(concat) + MLP, barrier-free ----------------
__global__ __launch_bounds__(256, 3) void node_kernel(
    const float* __restrict__ x, const float* __restrict__ aggr,
    const float* __restrict__ lng, const float* __restrict__ lnb,
    const unsigned short* __restrict__ Wu1p, const float* __restrict__ bu1p,
    const unsigned short* __restrict__ Wu2p, const float* __restrict__ bu2p,
    const unsigned short* __restrict__ Wu3p, const float* __restrict__ bu3,
    float* __restrict__ out) {
  __shared__ unsigned short sX[64 * STRN];  // [node][c] bf16, padded stride
  const int t = threadIdx.x;
  const int wave = t >> 6, lane = t & 63;

  // LayerNorm over cat=[x,aggr] (fp32). 4 threads per node (same wave).
  const int nl = t >> 2;
  const int part = t & 3;
  const long nodeG = (long)blockIdx.x * 64 + nl;
  const bool valid = nodeG < N_NODES;
  const float* src = (part < 2) ? (x + nodeG * 128 + part * 64)
                                : (aggr + nodeG * 128 + (part - 2) * 64);
  float s = 0.f, ss = 0.f;
  if (valid) {
#pragma unroll
    for (int i = 0; i < 16; i++) {
      float4 a = *(const float4*)(src + i * 4);
      s += a.x + a.y + a.z + a.w;
      ss += a.x * a.x + a.y * a.y + a.z * a.z + a.w * a.w;
    }
  }
  s += __shfl_xor(s, 1); s += __shfl_xor(s, 2);
  ss += __shfl_xor(ss, 1); ss += __shfl_xor(ss, 2);
  const float mean = s * (1.f / 256.f);
  const float var = ss * (1.f / 256.f) - mean * mean;
  const float rstd = rsqrtf(var + 1e-5f);
  const int cb = part * 64;
#pragma unroll
  for (int i = 0; i < 16; i++) {
    float4 a = valid ? *(const float4*)(src + i * 4) : make_float4(0.f, 0.f, 0.f, 0.f);
    int c = cb + i * 4;
    float4 g = *(const float4*)(const void*)&lng[c];
    float4 bb = *(const float4*)(const void*)&lnb[c];
    ushort4v p;
    p[0] = f2bf((a.x - mean) * rstd * g.x + bb.x);
    p[1] = f2bf((a.y - mean) * rstd * g.y + bb.y);
    p[2] = f2bf((a.z - mean) * rstd * g.z + bb.z);
    p[3] = f2bf((a.w - mean) * rstd * g.w + bb.w);
    *(ushort4v*)(void*)&sX[nl * STRN + c] = p;
  }

  const int nodeGBase = blockIdx.x * 64;
  layer_node<14, 8, false>(sX, Wu1p, bu1p, wave, lane, nodeGBase, nullptr);
  layer_node<12, 7, false>(sX, Wu2p, bu2p, wave, lane, nodeGBase, nullptr);
  layer_node<8, 6, true>(sX, Wu3p, bu3, wave, lane, nodeGBase, out);
}

// ---------------- launch ----------------
extern "C" void kernel_launch(void* const* d_in, const int* in_sizes, int n_in,
                              void* d_out, int out_size, void* d_ws, size_t ws_size,
                              hipStream_t stream) {
  const float* x    = (const float*)d_in[0];
  const int*   eidx = (const int*)d_in[1];
  const float* attr = (const float*)d_in[2];
  const float* Wm1  = (const float*)d_in[3];
  const float* bm1  = (const float*)d_in[4];
  const float* Wm2  = (const float*)d_in[5];
  const float* bm2  = (const float*)d_in[6];
  const float* Wm3  = (const float*)d_in[7];
  const float* bm3  = (const float*)d_in[8];
  const float* lng  = (const float*)d_in[9];
  const float* lnb  = (const float*)d_in[10];
  const float* Wu1  = (const float*)d_in[11];
  const float* bu1  = (const float*)d_in[12];
  const float* Wu2  = (const float*)d_in[13];
  const float* bu2  = (const float*)d_in[14];
  const float* Wu3  = (const float*)d_in[15];
  const float* bu3  = (const float*)d_in[16];
  float* out = (float*)d_out;

  char* ws = (char*)d_ws;
  float* aggr = (float*)(ws + WS_AGGR);
  int* counts = (int*)(ws + WS_COUNTS);
  int* offs   = (int*)(ws + WS_OFFS);
  int* parts  = (int*)(ws + WS_PART);
  int* rank   = (int*)(ws + WS_RANK);
  int2* pairs = (int2*)(ws + WS_PAIRS);
  unsigned short* Wm1p = (unsigned short*)(ws + WS_WM1);
  unsigned short* W2bf = (unsigned short*)(ws + WS_W2);
  unsigned short* W3bf = (unsigned short*)(ws + WS_W3);
  unsigned short* Wu1p = (unsigned short*)(ws + WS_WU1);
  unsigned short* Wu2p = (unsigned short*)(ws + WS_WU2);
  unsigned short* Wu3p = (unsigned short*)(ws + WS_WU3);
  float* bu1p = (float*)(ws + WS_BU1);
  float* bu2p = (float*)(ws + WS_BU2);

  const int* dst = eidx + N_EDGES;  // edge_index[1]

  hipMemsetAsync(counts, 0, 400384, stream);
  hipMemsetAsync(aggr, 0, (size_t)N_NODES * 128 * sizeof(float), stream);
  prep_kernel<<<634, 256, 0, stream>>>(Wm1, Wm2, Wm3, Wu1, Wu2, Wu3, bu1, bu2,
                                       Wm1p, W2bf, W3bf, Wu1p, Wu2p, Wu3p, bu1p, bu2p);

  hist_kernel<<<6250, 256, 0, stream>>>(dst, counts, rank);
  scanA_kernel<<<NBLK_SCAN, 256, 0, stream>>>(counts, offs, parts);
  scanB_kernel<<<1, 512, 0, stream>>>(parts);
  scanC_kernel<<<NBLK_SCAN, 256, 0, stream>>>(offs, parts);
  scatter_kernel<<<6250, 256, 0, stream>>>(dst, rank, offs, pairs);

  edge_kernel<<<N_EDGES / 128, 256, 0, stream>>>(attr, pairs, Wm1p, bm1, W2bf, bm2, W3bf,
                                                 bm3, aggr);
  node_kernel<<<(N_NODES + 63) / 64, 256, 0, stream>>>(x, aggr, lng, lnb, Wu1p, bu1p, Wu2p,
                                                       bu2p, Wu3p, bu3, out);
}